// Round 1
// baseline (9039.685 us; speedup 1.0000x reference)
//
#include <hip/hip_runtime.h>
#include <hip/hip_bf16.h>
#include <stdint.h>

// Problem dims
#define BB 64
#define SS 512
#define EE 256
#define HH 1024
#define VV 128

typedef __attribute__((ext_vector_type(8))) short short8;
typedef __attribute__((ext_vector_type(4))) float floatx4;

// ---- LDS layout (dynamic, one blob) ----
#define LDS_UFRAG 0                 // 3 gates * 32 ktiles * 64 lanes * 16B = 98304
#define LDS_HA    98304             // 16 rows * 2064B (1024 bf16 + pad)    = 33024
#define HA_ROW    2064
#define LDS_RED   131328            // 8 * 64 lanes * 16B fp32 = 8192
#define LDS_TOK   139520            // 16 * 512 u8 tokens = 8192
#define LDS_HOWN  147712            // 16*16 fp32 own-h slice = 1024
#define LDS_ZBUF  148736            // 16*16 fp32 z slice = 1024
#define LDS_XFER  149760            // 16*16 fp32 transfer tile (wave0 rh) = 1024
#define LDS_TOTAL 150784

// ---- workspace layout (bytes) ----
#define WS_TABLE  0                  // 128*3*1024 fp32 = 1572864
#define WS_RH     1572864            // 64*1024 bf16 = 131072
#define WS_FLAGS  1703936            // flagsA[256], flagsB[256] ints = 2048 (memset region)
#define WS_OUTS   2097152            // 512*64*1024 bf16 = 67108864

__device__ __forceinline__ unsigned short f2bf(float f) {
  union { float f; unsigned int i; } x; x.f = f;
  unsigned int r = x.i + 0x7fffu + ((x.i >> 16) & 1u);
  return (unsigned short)(r >> 16);
}
__device__ __forceinline__ unsigned long long pack4bf(float a, float b, float c, float d) {
  unsigned int lo = ((unsigned int)f2bf(b) << 16) | f2bf(a);
  unsigned int hi = ((unsigned int)f2bf(d) << 16) | f2bf(c);
  return ((unsigned long long)hi << 32) | lo;
}
// sc1 store: lands at the cross-XCD coherence point, never dirties L2.
__device__ __forceinline__ void st_agent_b64(unsigned long long* p, unsigned long long v) {
  __hip_atomic_store(p, v, __ATOMIC_RELAXED, __HIP_MEMORY_SCOPE_AGENT);
}

// table[v][g][j] = sum_e emb[v][e] * W_g[j][e] + 2*b_g[j]   (fp32 in, fp32 out)
__global__ void __launch_bounds__(256)
table_kernel(const float* __restrict__ emb,
             const float* __restrict__ Wr, const float* __restrict__ br,
             const float* __restrict__ Wz, const float* __restrict__ bz,
             const float* __restrict__ Wh, const float* __restrict__ bh,
             float* __restrict__ table) {
  int id = blockIdx.x * 256 + threadIdx.x;          // 128*3*1024 = 393216 exact
  int v = id / 3072;
  int rem = id - v * 3072;
  int g = rem >> 10;
  int j = rem & 1023;
  const float* W  = (g == 0) ? Wr : (g == 1) ? Wz : Wh;
  const float* bb = (g == 0) ? br : (g == 1) ? bz : bh;
  const float4* ev = (const float4*)(emb + (size_t)v * EE);
  const float4* wv = (const float4*)(W + (size_t)j * EE);
  float acc = 2.f * bb[j];                          // faithful: bias added twice
  for (int e = 0; e < EE / 4; ++e) {
    float4 a = ev[e], b4 = wv[e];
    acc += a.x * b4.x + a.y * b4.y + a.z * b4.z + a.w * b4.w;
  }
  table[id] = acc;
}

// Coalesced bypass poll: 16 lanes read the group's 64 flags as dwordx4 sc0 sc1;
// wave returns when all 64 flags >= tgt. Lanes >=16 duplicate lane&15's address
// (coalescer broadcasts). Flags are written by independent per-WG release stores.
__device__ __forceinline__ void poll_flags(const int* flags, int tgt, int lane) {
  const char* fp = (const char*)flags + (lane & 15) * 16;
  for (;;) {
    uint4 f;
    asm volatile("global_load_dwordx4 %0, %1, off sc0 sc1\n\t"
                 "s_waitcnt vmcnt(0)"
                 : "=v"(f) : "v"(fp) : "memory");
    bool ok = ((int)f.x >= tgt) & ((int)f.y >= tgt) &
              ((int)f.z >= tgt) & ((int)f.w >= tgt);
    if (__all(ok)) break;
    __builtin_amdgcn_s_sleep(1);
  }
}

// Persistent cooperative GRU. 256 blocks x 256 threads, 1 block/CU.
// blockIdx: group = >>6 (batch slice of 16), col = &63 (16 output columns).
__global__ void __launch_bounds__(256, 1)
gru_kernel(const int* __restrict__ x,
           const float* __restrict__ Ur, const float* __restrict__ Uz,
           const float* __restrict__ Uh,
           const float* __restrict__ table,
           unsigned short* __restrict__ outs,     // [S][B][H] bf16 (sc1-written, cached reads)
           unsigned short* __restrict__ rhbuf,    // [B][H] bf16 (sc1-written, bypass reads)
           float* __restrict__ hlast,             // [B][H] fp32 -> d_out tail
           int* __restrict__ flagsA, int* __restrict__ flagsB) {
  extern __shared__ char smem[];
  const int tid = threadIdx.x;
  const int lane = tid & 63;
  const int w = tid >> 6;            // wave 0..3, owns K-slice [w*256, w*256+256)
  const int wg = blockIdx.x;
  const int group = wg >> 6;
  const int col = wg & 63;
  const int j0 = col << 4;

  float* red   = (float*)(smem + LDS_RED);
  float* h_own = (float*)(smem + LDS_HOWN);
  float* zbuf  = (float*)(smem + LDS_ZBUF);
  float* xfer  = (float*)(smem + LDS_XFER);
  const unsigned char* toks = (const unsigned char*)(smem + LDS_TOK);
  const int* myflagsA = flagsA + group * 64;
  const int* myflagsB = flagsB + group * 64;

  // ---- init: U (fp32) -> LDS bf16 in MFMA B-frag order; tokens; h_own = 0 ----
  {
    const float* Us[3] = {Ur, Uz, Uh};
    for (int c = w * 24; c < w * 24 + 24; ++c) {     // 96 (gate,ktile) chunks / 4 waves
      int g = c >> 5, kt = c & 31;
      // B-frag: lane holds U[j0+(lane&15)][kt*32 + (lane>>4)*8 + 0..7]
      const float* src = Us[g] + (size_t)(j0 + (lane & 15)) * HH + kt * 32 + (lane >> 4) * 8;
      float4 f0 = ((const float4*)src)[0];
      float4 f1 = ((const float4*)src)[1];
      short8 frag;
      frag[0] = (short)f2bf(f0.x); frag[1] = (short)f2bf(f0.y);
      frag[2] = (short)f2bf(f0.z); frag[3] = (short)f2bf(f0.w);
      frag[4] = (short)f2bf(f1.x); frag[5] = (short)f2bf(f1.y);
      frag[6] = (short)f2bf(f1.z); frag[7] = (short)f2bf(f1.w);
      *(short8*)(smem + ((g * 32 + kt) * 64 + lane) * 16) = frag;
    }
    for (int i = tid; i < 16 * SS; i += 256) {
      int b = i >> 9, t = i & 511;
      smem[LDS_TOK + i] = (char)x[(size_t)(group * 16 + b) * SS + t];
    }
    ((float*)(smem + LDS_HOWN))[tid] = 0.f;
  }
  __syncthreads();

  for (int t = 0; t < SS; ++t) {
    // ================= phase A : r, z =================
    if (t > 0) {
      if (w == 0) poll_flags(myflagsB, t, lane);
      __syncthreads();
      // plain cached staging: outs[t-1] lines are first-touched after the flag,
      // written once via sc1 (never stale in L2; dispatch-start inv covers replays).
      const uint4* hsrc = (const uint4*)(outs + (size_t)((t - 1) * BB + group * 16) * HH);
#pragma unroll
      for (int i = 0; i < 8; ++i) {
        int c = w * 512 + i * 64 + lane;            // 2048 x 16B chunks
        int b = c >> 7, k = c & 127;
        *(uint4*)(smem + LDS_HA + b * HA_ROW + k * 16) = hsrc[c];
      }
    } else {
      uint4 z4 = {0, 0, 0, 0};
      for (int c = tid; c < 16 * 129; c += 256)
        *(uint4*)(smem + LDS_HA + c * 16) = z4;
    }
    __syncthreads();

    floatx4 accr = {0,0,0,0}, accz = {0,0,0,0};
    {
      const int abase = (lane & 15) * HA_ROW + (lane >> 4) * 16;
      for (int kt = w * 8; kt < w * 8 + 8; ++kt) {
        short8 a   = *(const short8*)(smem + LDS_HA + abase + kt * 64);
        short8 br_ = *(const short8*)(smem + ((0 * 32 + kt) * 64 + lane) * 16);
        short8 bz_ = *(const short8*)(smem + ((1 * 32 + kt) * 64 + lane) * 16);
        accr = __builtin_amdgcn_mfma_f32_16x16x32_bf16(a, br_, accr, 0, 0, 0);
        accz = __builtin_amdgcn_mfma_f32_16x16x32_bf16(a, bz_, accz, 0, 0, 0);
      }
    }
    *(floatx4*)(red + ((w * 2 + 0) * 64 + lane) * 4) = accr;
    *(floatx4*)(red + ((w * 2 + 1) * 64 + lane) * 4) = accz;
    __syncthreads();

    if (w == 0) {           // finalize r; pack r*h row-contiguous; sc1-store to handoff
      floatx4 s = {0,0,0,0};
      for (int ww = 0; ww < 4; ++ww) s += *(const floatx4*)(red + ((ww * 2) * 64 + lane) * 4);
      const int j = lane & 15;
#pragma unroll
      for (int i = 0; i < 4; ++i) {
        int b = (lane >> 4) * 4 + i;              // C-layout: row=(lane>>4)*4+reg, col=lane&15
        int tok = toks[b * SS + t];
        float xr = table[tok * 3072 + j0 + j];
        float r = 1.f / (1.f + __expf(-(s[i] + xr)));
        xfer[b * 16 + j] = r * h_own[b * 16 + j];
      }
      asm volatile("s_waitcnt lgkmcnt(0)" ::: "memory");   // cross-lane LDS RAW (same wave)
      int row = lane >> 2, c0 = (lane & 3) * 4;
      unsigned long long pk = pack4bf(xfer[row * 16 + c0 + 0], xfer[row * 16 + c0 + 1],
                                      xfer[row * 16 + c0 + 2], xfer[row * 16 + c0 + 3]);
      st_agent_b64((unsigned long long*)(rhbuf + (size_t)(group * 16 + row) * HH + j0 + c0), pk);
      if (lane == 0)   // release store: vmcnt(0) drains wave0's sc1 stores before flag
        __hip_atomic_store(flagsA + wg, t + 1, __ATOMIC_RELEASE, __HIP_MEMORY_SCOPE_AGENT);
    } else if (w == 1) {    // finalize z, keep in LDS
      floatx4 s = {0,0,0,0};
      for (int ww = 0; ww < 4; ++ww) s += *(const floatx4*)(red + ((ww * 2 + 1) * 64 + lane) * 4);
      const int j = lane & 15;
#pragma unroll
      for (int i = 0; i < 4; ++i) {
        int b = (lane >> 4) * 4 + i;
        int tok = toks[b * SS + t];
        float xz = table[tok * 3072 + 1024 + j0 + j];
        zbuf[b * 16 + j] = 1.f / (1.f + __expf(-(s[i] + xz)));
      }
    }

    // ================= phase B : h_tilde, h_new =================
    if (w == 0) poll_flags(myflagsA, t + 1, lane);
    __syncthreads();
    {
      // rh addresses are reused every step -> must bypass L2: coalesced dwordx4 sc0 sc1
      const char* rb = (const char*)(rhbuf + (size_t)group * 16 * HH) + (w * 512 + lane) * 16;
      const char* p0 = rb;
      const char* p1 = rb + 4096;
      uint4 r0, r1, r2, r3, r4, r5, r6, r7;
      asm volatile(
        "global_load_dwordx4 %0, %8, off sc0 sc1\n\t"
        "global_load_dwordx4 %1, %8, off offset:1024 sc0 sc1\n\t"
        "global_load_dwordx4 %2, %8, off offset:2048 sc0 sc1\n\t"
        "global_load_dwordx4 %3, %8, off offset:3072 sc0 sc1\n\t"
        "global_load_dwordx4 %4, %9, off sc0 sc1\n\t"
        "global_load_dwordx4 %5, %9, off offset:1024 sc0 sc1\n\t"
        "global_load_dwordx4 %6, %9, off offset:2048 sc0 sc1\n\t"
        "global_load_dwordx4 %7, %9, off offset:3072 sc0 sc1\n\t"
        "s_waitcnt vmcnt(0)"
        : "=v"(r0), "=v"(r1), "=v"(r2), "=v"(r3),
          "=v"(r4), "=v"(r5), "=v"(r6), "=v"(r7)
        : "v"(p0), "v"(p1)
        : "memory");
      // chunk c_i = w*512 + i*64 + lane  ->  b = w*4 + i/2, k = (i&1)*64 + lane
      uint4 rr[8] = {r0, r1, r2, r3, r4, r5, r6, r7};
#pragma unroll
      for (int i = 0; i < 8; ++i) {
        int b = w * 4 + (i >> 1), k = ((i & 1) << 6) + lane;
        *(uint4*)(smem + LDS_HA + b * HA_ROW + k * 16) = rr[i];
      }
    }
    __syncthreads();

    floatx4 acch = {0,0,0,0};
    {
      const int abase = (lane & 15) * HA_ROW + (lane >> 4) * 16;
      for (int kt = w * 8; kt < w * 8 + 8; ++kt) {
        short8 a   = *(const short8*)(smem + LDS_HA + abase + kt * 64);
        short8 bh_ = *(const short8*)(smem + ((2 * 32 + kt) * 64 + lane) * 16);
        acch = __builtin_amdgcn_mfma_f32_16x16x32_bf16(a, bh_, acch, 0, 0, 0);
      }
    }
    *(floatx4*)(red + (w * 64 + lane) * 4) = acch;
    __syncthreads();

    if (w == 2) {
      floatx4 s = {0,0,0,0};
      for (int ww = 0; ww < 4; ++ww) s += *(const floatx4*)(red + (ww * 64 + lane) * 4);
      const int j = lane & 15;
#pragma unroll
      for (int i = 0; i < 4; ++i) {
        int b = (lane >> 4) * 4 + i;
        int tok = toks[b * SS + t];
        float xh = table[tok * 3072 + 2048 + j0 + j];
        float ht = tanhf(s[i] + xh);
        float z = zbuf[b * 16 + j];
        float hp = h_own[b * 16 + j];
        h_own[b * 16 + j] = (1.f - z) * ht + z * hp;  // fp32 master copy persists
      }
      asm volatile("s_waitcnt lgkmcnt(0)" ::: "memory");   // cross-lane LDS RAW (same wave)
      int row = lane >> 2, c0 = (lane & 3) * 4;
      float f0 = h_own[row * 16 + c0 + 0], f1 = h_own[row * 16 + c0 + 1];
      float f2 = h_own[row * 16 + c0 + 2], f3 = h_own[row * 16 + c0 + 3];
      st_agent_b64((unsigned long long*)(outs + (size_t)(t * BB + group * 16 + row) * HH + j0 + c0),
                   pack4bf(f0, f1, f2, f3));
      if (t == SS - 1) {
        float4 v4 = {f0, f1, f2, f3};
        *(float4*)(hlast + (size_t)(group * 16 + row) * HH + j0 + c0) = v4;  // fp32, plain
      }
      if (lane == 0) // release store: drains wave2's sc1 outs stores first
        __hip_atomic_store(flagsB + wg, t + 1, __ATOMIC_RELEASE, __HIP_MEMORY_SCOPE_AGENT);
    }
    __syncthreads();
  }
}

// logits[b][s][v] = outs[s][b][:] . Wfc[v][:] + b_fc[v]   (fp32 out)
__global__ void __launch_bounds__(256)
logits_kernel(const unsigned short* __restrict__ outs, const float* __restrict__ Wfc,
              const float* __restrict__ bfc, float* __restrict__ out) {
  const int lane = threadIdx.x & 63;
  const int mt = blockIdx.x * 4 + (threadIdx.x >> 6);  // M-tile 0..2047 (M = S*B = 32768)
  const size_t arow = (size_t)(mt * 16 + (lane & 15)) * HH + (lane >> 4) * 8;
  floatx4 zero = {0,0,0,0};
  floatx4 acc[8];
#pragma unroll
  for (int n = 0; n < 8; ++n) acc[n] = zero;
  for (int kt = 0; kt < 32; ++kt) {
    short8 a = *(const short8*)(outs + arow + kt * 32);
#pragma unroll
    for (int n = 0; n < 8; ++n) {
      const float* wsrc = Wfc + (size_t)(n * 16 + (lane & 15)) * HH + kt * 32 + (lane >> 4) * 8;
      float4 f0 = ((const float4*)wsrc)[0];
      float4 f1 = ((const float4*)wsrc)[1];
      short8 b;
      b[0] = (short)f2bf(f0.x); b[1] = (short)f2bf(f0.y);
      b[2] = (short)f2bf(f0.z); b[3] = (short)f2bf(f0.w);
      b[4] = (short)f2bf(f1.x); b[5] = (short)f2bf(f1.y);
      b[6] = (short)f2bf(f1.z); b[7] = (short)f2bf(f1.w);
      acc[n] = __builtin_amdgcn_mfma_f32_16x16x32_bf16(a, b, acc[n], 0, 0, 0);
    }
  }
#pragma unroll
  for (int n = 0; n < 8; ++n) {
    int v = n * 16 + (lane & 15);
    float bias = bfc[v];
#pragma unroll
    for (int i = 0; i < 4; ++i) {
      int m = mt * 16 + (lane >> 4) * 4 + i;
      int s = m >> 6, b = m & 63;
      out[((size_t)b * SS + s) * VV + v] = acc[n][i] + bias;
    }
  }
}

extern "C" void kernel_launch(void* const* d_in, const int* in_sizes, int n_in,
                              void* d_out, int out_size, void* d_ws, size_t ws_size,
                              hipStream_t stream) {
  const int*   x    = (const int*)d_in[0];
  const float* emb  = (const float*)d_in[1];
  const float* W_r  = (const float*)d_in[2];
  const float* U_r  = (const float*)d_in[3];
  const float* b_r  = (const float*)d_in[4];
  const float* W_z  = (const float*)d_in[5];
  const float* U_z  = (const float*)d_in[6];
  const float* b_z  = (const float*)d_in[7];
  const float* W_h  = (const float*)d_in[8];
  const float* U_h  = (const float*)d_in[9];
  const float* b_h  = (const float*)d_in[10];
  const float* W_fc = (const float*)d_in[11];
  const float* b_fc = (const float*)d_in[12];

  char* ws = (char*)d_ws;
  float*          table  = (float*)(ws + WS_TABLE);
  unsigned short* rhbuf  = (unsigned short*)(ws + WS_RH);
  int*            flagsA = (int*)(ws + WS_FLAGS);
  int*            flagsB = (int*)(ws + WS_FLAGS + 1024);
  unsigned short* outs   = (unsigned short*)(ws + WS_OUTS);
  float*          out    = (float*)d_out;
  float*          hlast  = out + (size_t)BB * SS * VV;   // output 1, fp32

  // flags must start at 0 every call (ws is re-poisoned to 0xAA)
  hipMemsetAsync(ws + WS_FLAGS, 0, 2048, stream);

  table_kernel<<<dim3((128 * 3 * 1024) / 256), dim3(256), 0, stream>>>(
      emb, W_r, b_r, W_z, b_z, W_h, b_h, table);

  hipFuncSetAttribute(reinterpret_cast<const void*>(gru_kernel),
                      hipFuncAttributeMaxDynamicSharedMemorySize, LDS_TOTAL);
  void* args[] = {(void*)&x, (void*)&U_r, (void*)&U_z, (void*)&U_h, (void*)&table,
                  (void*)&outs, (void*)&rhbuf, (void*)&hlast, (void*)&flagsA, (void*)&flagsB};
  hipLaunchCooperativeKernel(reinterpret_cast<void*>(gru_kernel), dim3(256), dim3(256),
                             args, (unsigned)LDS_TOTAL, stream);

  logits_kernel<<<dim3(512), dim3(256), 0, stream>>>(outs, W_fc, b_fc, out);
}

// Round 2
// 5813.739 us; speedup vs baseline: 1.5549x; 1.5549x over previous
//
#include <hip/hip_runtime.h>
#include <hip/hip_bf16.h>
#include <stdint.h>

// Problem dims
#define BB 64
#define SS 512
#define EE 256
#define HH 1024
#define VV 128

typedef __attribute__((ext_vector_type(8))) short short8;
typedef __attribute__((ext_vector_type(4))) float floatx4;

// ---- LDS layout (dynamic, one blob) ----
#define LDS_UFRAG 0                 // 3 gates * 32 ktiles * 64 lanes * 16B = 98304
#define LDS_HA    98304             // 16 rows * 2064B (1024 bf16 + pad)    = 33024
#define HA_ROW    2064
#define LDS_RED   131328            // 8 * 64 lanes * 16B fp32 = 8192
#define LDS_TOK   139520            // 16 * 512 u8 tokens = 8192
#define LDS_HOWN  147712            // 16*16 fp32 own-h slice = 1024
#define LDS_ZBUF  148736            // 16*16 fp32 z slice = 1024
#define LDS_XFER  149760            // 16*16 fp32 transfer tile (wave0 rh) = 1024
#define LDS_TOTAL 150784

// ---- workspace layout (bytes) ----
#define WS_TABLE  0                  // 128*3*1024 fp32 = 1572864
#define WS_RH     1572864            // 64*1024 bf16 = 131072
#define WS_FLAGS  1703936            // flagsA[256], flagsB[256] ints = 2048 (memset region)
#define WS_OUTS   2097152            // 512*64*1024 bf16 = 67108864

__device__ __forceinline__ unsigned short f2bf(float f) {
  union { float f; unsigned int i; } x; x.f = f;
  unsigned int r = x.i + 0x7fffu + ((x.i >> 16) & 1u);
  return (unsigned short)(r >> 16);
}
__device__ __forceinline__ unsigned long long pack4bf(float a, float b, float c, float d) {
  unsigned int lo = ((unsigned int)f2bf(b) << 16) | f2bf(a);
  unsigned int hi = ((unsigned int)f2bf(d) << 16) | f2bf(c);
  return ((unsigned long long)hi << 32) | lo;
}
// sc1 store: lands at the cross-XCD coherence point, never dirties L2.
__device__ __forceinline__ void st_agent_b64(unsigned long long* p, unsigned long long v) {
  __hip_atomic_store(p, v, __ATOMIC_RELAXED, __HIP_MEMORY_SCOPE_AGENT);
}
// Hand-rolled release: our data stores are sc1 (bypass L2, land at LLC), so a
// full RELEASE's L2 writeback (buffer_wbl2) is pure overhead. vmcnt(0) drains
// the sc1 data stores to the coherence point; then a RELAXED agent (sc1) flag
// store is ordered behind them at the LLC.
__device__ __forceinline__ void flag_release(int* p, int v) {
  asm volatile("s_waitcnt vmcnt(0)" ::: "memory");
  __hip_atomic_store(p, v, __ATOMIC_RELAXED, __HIP_MEMORY_SCOPE_AGENT);
}

// table[v][g][j] = sum_e emb[v][e] * W_g[j][e] + 2*b_g[j]   (fp32 in, fp32 out)
__global__ void __launch_bounds__(256)
table_kernel(const float* __restrict__ emb,
             const float* __restrict__ Wr, const float* __restrict__ br,
             const float* __restrict__ Wz, const float* __restrict__ bz,
             const float* __restrict__ Wh, const float* __restrict__ bh,
             float* __restrict__ table) {
  int id = blockIdx.x * 256 + threadIdx.x;          // 128*3*1024 = 393216 exact
  int v = id / 3072;
  int rem = id - v * 3072;
  int g = rem >> 10;
  int j = rem & 1023;
  const float* W  = (g == 0) ? Wr : (g == 1) ? Wz : Wh;
  const float* bb = (g == 0) ? br : (g == 1) ? bz : bh;
  const float4* ev = (const float4*)(emb + (size_t)v * EE);
  const float4* wv = (const float4*)(W + (size_t)j * EE);
  float acc = 2.f * bb[j];                          // faithful: bias added twice
  for (int e = 0; e < EE / 4; ++e) {
    float4 a = ev[e], b4 = wv[e];
    acc += a.x * b4.x + a.y * b4.y + a.z * b4.z + a.w * b4.w;
  }
  table[id] = acc;
}

// Coalesced bypass poll: 16 lanes read the group's 64 flags as dwordx4 sc0 sc1;
// wave returns when all 64 flags >= tgt. Lanes >=16 duplicate lane&15's address
// (coalescer broadcasts). Flags are written by independent per-WG relaxed
// agent stores (ordered behind data by the producer's vmcnt(0) drain).
__device__ __forceinline__ void poll_flags(const int* flags, int tgt, int lane) {
  const char* fp = (const char*)flags + (lane & 15) * 16;
  for (;;) {
    uint4 f;
    asm volatile("global_load_dwordx4 %0, %1, off sc0 sc1\n\t"
                 "s_waitcnt vmcnt(0)"
                 : "=v"(f) : "v"(fp) : "memory");
    bool ok = ((int)f.x >= tgt) & ((int)f.y >= tgt) &
              ((int)f.z >= tgt) & ((int)f.w >= tgt);
    if (__all(ok)) break;
    __builtin_amdgcn_s_sleep(1);
  }
}

// Persistent cooperative GRU. 256 blocks x 256 threads, 1 block/CU.
// blockIdx: group = >>6 (batch slice of 16), col = &63 (16 output columns).
__global__ void __launch_bounds__(256, 1)
gru_kernel(const int* __restrict__ x,
           const float* __restrict__ Ur, const float* __restrict__ Uz,
           const float* __restrict__ Uh,
           const float* __restrict__ table,
           unsigned short* __restrict__ outs,     // [S][B][H] bf16 (sc1-written, cached reads)
           unsigned short* __restrict__ rhbuf,    // [B][H] bf16 (sc1-written, bypass reads)
           float* __restrict__ hlast,             // [B][H] fp32 -> d_out tail
           int* __restrict__ flagsA, int* __restrict__ flagsB) {
  extern __shared__ char smem[];
  const int tid = threadIdx.x;
  const int lane = tid & 63;
  const int w = tid >> 6;            // wave 0..3, owns K-slice [w*256, w*256+256)
  const int wg = blockIdx.x;
  const int group = wg >> 6;
  const int col = wg & 63;
  const int j0 = col << 4;

  float* red   = (float*)(smem + LDS_RED);
  float* h_own = (float*)(smem + LDS_HOWN);
  float* zbuf  = (float*)(smem + LDS_ZBUF);
  float* xfer  = (float*)(smem + LDS_XFER);
  const unsigned char* toks = (const unsigned char*)(smem + LDS_TOK);
  const int* myflagsA = flagsA + group * 64;
  const int* myflagsB = flagsB + group * 64;

  // ---- init: U (fp32) -> LDS bf16 in MFMA B-frag order; tokens; h_own = 0 ----
  {
    const float* Us[3] = {Ur, Uz, Uh};
    for (int c = w * 24; c < w * 24 + 24; ++c) {     // 96 (gate,ktile) chunks / 4 waves
      int g = c >> 5, kt = c & 31;
      // B-frag: lane holds U[j0+(lane&15)][kt*32 + (lane>>4)*8 + 0..7]
      const float* src = Us[g] + (size_t)(j0 + (lane & 15)) * HH + kt * 32 + (lane >> 4) * 8;
      float4 f0 = ((const float4*)src)[0];
      float4 f1 = ((const float4*)src)[1];
      short8 frag;
      frag[0] = (short)f2bf(f0.x); frag[1] = (short)f2bf(f0.y);
      frag[2] = (short)f2bf(f0.z); frag[3] = (short)f2bf(f0.w);
      frag[4] = (short)f2bf(f1.x); frag[5] = (short)f2bf(f1.y);
      frag[6] = (short)f2bf(f1.z); frag[7] = (short)f2bf(f1.w);
      *(short8*)(smem + ((g * 32 + kt) * 64 + lane) * 16) = frag;
    }
    for (int i = tid; i < 16 * SS; i += 256) {
      int b = i >> 9, t = i & 511;
      smem[LDS_TOK + i] = (char)x[(size_t)(group * 16 + b) * SS + t];
    }
    ((float*)(smem + LDS_HOWN))[tid] = 0.f;
  }
  __syncthreads();

  for (int t = 0; t < SS; ++t) {
    // ---- prefetch this step's x-projection rows (tokens known ahead of time;
    // pulls the table L2 read off the post-MFMA critical path). gate = w.
    float xpre[4];
    if (w < 3) {
      const int j = lane & 15;
      const float* tb = table + w * 1024 + j0 + j;
#pragma unroll
      for (int i = 0; i < 4; ++i) {
        int b = (lane >> 4) * 4 + i;
        int tok = toks[b * SS + t];
        xpre[i] = tb[tok * 3072];
      }
    }

    // ================= phase A : r, z =================
    if (t > 0) {
      if (w == 0) poll_flags(myflagsB, t, lane);
      __syncthreads();
      // plain cached staging: outs[t-1] lines are first-touched after the flag,
      // written once via sc1 (never stale in L2; dispatch-start inv covers replays).
      const uint4* hsrc = (const uint4*)(outs + (size_t)((t - 1) * BB + group * 16) * HH);
#pragma unroll
      for (int i = 0; i < 8; ++i) {
        int c = w * 512 + i * 64 + lane;            // 2048 x 16B chunks
        int b = c >> 7, k = c & 127;
        *(uint4*)(smem + LDS_HA + b * HA_ROW + k * 16) = hsrc[c];
      }
    } else {
      uint4 z4 = {0, 0, 0, 0};
      for (int c = tid; c < 16 * 129; c += 256)
        *(uint4*)(smem + LDS_HA + c * 16) = z4;
    }
    __syncthreads();

    floatx4 accr = {0,0,0,0}, accz = {0,0,0,0};
    {
      const int abase = (lane & 15) * HA_ROW + (lane >> 4) * 16;
      for (int kt = w * 8; kt < w * 8 + 8; ++kt) {
        short8 a   = *(const short8*)(smem + LDS_HA + abase + kt * 64);
        short8 br_ = *(const short8*)(smem + ((0 * 32 + kt) * 64 + lane) * 16);
        short8 bz_ = *(const short8*)(smem + ((1 * 32 + kt) * 64 + lane) * 16);
        accr = __builtin_amdgcn_mfma_f32_16x16x32_bf16(a, br_, accr, 0, 0, 0);
        accz = __builtin_amdgcn_mfma_f32_16x16x32_bf16(a, bz_, accz, 0, 0, 0);
      }
    }
    *(floatx4*)(red + ((w * 2 + 0) * 64 + lane) * 4) = accr;
    *(floatx4*)(red + ((w * 2 + 1) * 64 + lane) * 4) = accz;
    __syncthreads();

    if (w == 0) {           // finalize r; pack r*h row-contiguous; sc1-store to handoff
      floatx4 s = {0,0,0,0};
      for (int ww = 0; ww < 4; ++ww) s += *(const floatx4*)(red + ((ww * 2) * 64 + lane) * 4);
      const int j = lane & 15;
#pragma unroll
      for (int i = 0; i < 4; ++i) {
        int b = (lane >> 4) * 4 + i;              // C-layout: row=(lane>>4)*4+reg, col=lane&15
        float r = 1.f / (1.f + __expf(-(s[i] + xpre[i])));
        xfer[b * 16 + j] = r * h_own[b * 16 + j];
      }
      asm volatile("s_waitcnt lgkmcnt(0)" ::: "memory");   // cross-lane LDS RAW (same wave)
      int row = lane >> 2, c0 = (lane & 3) * 4;
      unsigned long long pk = pack4bf(xfer[row * 16 + c0 + 0], xfer[row * 16 + c0 + 1],
                                      xfer[row * 16 + c0 + 2], xfer[row * 16 + c0 + 3]);
      st_agent_b64((unsigned long long*)(rhbuf + (size_t)(group * 16 + row) * HH + j0 + c0), pk);
      // release: vmcnt(0) drains wave0's sc1 stores, then relaxed sc1 flag
      asm volatile("s_waitcnt vmcnt(0)" ::: "memory");
      if (lane == 0)
        __hip_atomic_store(flagsA + wg, t + 1, __ATOMIC_RELAXED, __HIP_MEMORY_SCOPE_AGENT);
    } else if (w == 1) {    // finalize z, keep in LDS
      floatx4 s = {0,0,0,0};
      for (int ww = 0; ww < 4; ++ww) s += *(const floatx4*)(red + ((ww * 2 + 1) * 64 + lane) * 4);
      const int j = lane & 15;
#pragma unroll
      for (int i = 0; i < 4; ++i) {
        int b = (lane >> 4) * 4 + i;
        zbuf[b * 16 + j] = 1.f / (1.f + __expf(-(s[i] + xpre[i])));
      }
    }

    // ================= phase B : h_tilde, h_new =================
    // poll by idle wave3: overlaps the r-finalize running on wave0
    if (w == 3) poll_flags(myflagsA, t + 1, lane);
    __syncthreads();
    {
      // rh addresses are reused every step -> must bypass L2: coalesced dwordx4 sc0 sc1
      const char* rb = (const char*)(rhbuf + (size_t)group * 16 * HH) + (w * 512 + lane) * 16;
      const char* p0 = rb;
      const char* p1 = rb + 4096;
      uint4 r0, r1, r2, r3, r4, r5, r6, r7;
      asm volatile(
        "global_load_dwordx4 %0, %8, off sc0 sc1\n\t"
        "global_load_dwordx4 %1, %8, off offset:1024 sc0 sc1\n\t"
        "global_load_dwordx4 %2, %8, off offset:2048 sc0 sc1\n\t"
        "global_load_dwordx4 %3, %8, off offset:3072 sc0 sc1\n\t"
        "global_load_dwordx4 %4, %9, off sc0 sc1\n\t"
        "global_load_dwordx4 %5, %9, off offset:1024 sc0 sc1\n\t"
        "global_load_dwordx4 %6, %9, off offset:2048 sc0 sc1\n\t"
        "global_load_dwordx4 %7, %9, off offset:3072 sc0 sc1\n\t"
        "s_waitcnt vmcnt(0)"
        : "=v"(r0), "=v"(r1), "=v"(r2), "=v"(r3),
          "=v"(r4), "=v"(r5), "=v"(r6), "=v"(r7)
        : "v"(p0), "v"(p1)
        : "memory");
      // chunk c_i = w*512 + i*64 + lane  ->  b = w*4 + i/2, k = (i&1)*64 + lane
      uint4 rr[8] = {r0, r1, r2, r3, r4, r5, r6, r7};
#pragma unroll
      for (int i = 0; i < 8; ++i) {
        int b = w * 4 + (i >> 1), k = ((i & 1) << 6) + lane;
        *(uint4*)(smem + LDS_HA + b * HA_ROW + k * 16) = rr[i];
      }
    }
    __syncthreads();

    floatx4 acch = {0,0,0,0};
    {
      const int abase = (lane & 15) * HA_ROW + (lane >> 4) * 16;
      for (int kt = w * 8; kt < w * 8 + 8; ++kt) {
        short8 a   = *(const short8*)(smem + LDS_HA + abase + kt * 64);
        short8 bh_ = *(const short8*)(smem + ((2 * 32 + kt) * 64 + lane) * 16);
        acch = __builtin_amdgcn_mfma_f32_16x16x32_bf16(a, bh_, acch, 0, 0, 0);
      }
    }
    *(floatx4*)(red + (w * 64 + lane) * 4) = acch;
    __syncthreads();

    if (w == 2) {
      floatx4 s = {0,0,0,0};
      for (int ww = 0; ww < 4; ++ww) s += *(const floatx4*)(red + (ww * 64 + lane) * 4);
      const int j = lane & 15;
#pragma unroll
      for (int i = 0; i < 4; ++i) {
        int b = (lane >> 4) * 4 + i;
        float ht = tanhf(s[i] + xpre[i]);
        float z = zbuf[b * 16 + j];
        float hp = h_own[b * 16 + j];
        h_own[b * 16 + j] = (1.f - z) * ht + z * hp;  // fp32 master copy persists
      }
      asm volatile("s_waitcnt lgkmcnt(0)" ::: "memory");   // cross-lane LDS RAW (same wave)
      int row = lane >> 2, c0 = (lane & 3) * 4;
      float f0 = h_own[row * 16 + c0 + 0], f1 = h_own[row * 16 + c0 + 1];
      float f2 = h_own[row * 16 + c0 + 2], f3 = h_own[row * 16 + c0 + 3];
      st_agent_b64((unsigned long long*)(outs + (size_t)(t * BB + group * 16 + row) * HH + j0 + c0),
                   pack4bf(f0, f1, f2, f3));
      if (t == SS - 1) {
        float4 v4 = {f0, f1, f2, f3};
        *(float4*)(hlast + (size_t)(group * 16 + row) * HH + j0 + c0) = v4;  // fp32, plain
      }
      // release: vmcnt(0) drains wave2's sc1 outs stores, then relaxed sc1 flag
      asm volatile("s_waitcnt vmcnt(0)" ::: "memory");
      if (lane == 0)
        __hip_atomic_store(flagsB + wg, t + 1, __ATOMIC_RELAXED, __HIP_MEMORY_SCOPE_AGENT);
    }
    // NOTE: former end-of-loop __syncthreads removed — top-of-loop poll(own
    // flagB included) + post-poll sync + post-gather sync cover all LDS hazards.
  }
}

// logits[b][s][v] = outs[s][b][:] . Wfc[v][:] + b_fc[v]   (fp32 out)
__global__ void __launch_bounds__(256)
logits_kernel(const unsigned short* __restrict__ outs, const float* __restrict__ Wfc,
              const float* __restrict__ bfc, float* __restrict__ out) {
  const int lane = threadIdx.x & 63;
  const int mt = blockIdx.x * 4 + (threadIdx.x >> 6);  // M-tile 0..2047 (M = S*B = 32768)
  const size_t arow = (size_t)(mt * 16 + (lane & 15)) * HH + (lane >> 4) * 8;
  floatx4 zero = {0,0,0,0};
  floatx4 acc[8];
#pragma unroll
  for (int n = 0; n < 8; ++n) acc[n] = zero;
  for (int kt = 0; kt < 32; ++kt) {
    short8 a = *(const short8*)(outs + arow + kt * 32);
#pragma unroll
    for (int n = 0; n < 8; ++n) {
      const float* wsrc = Wfc + (size_t)(n * 16 + (lane & 15)) * HH + kt * 32 + (lane >> 4) * 8;
      float4 f0 = ((const float4*)wsrc)[0];
      float4 f1 = ((const float4*)wsrc)[1];
      short8 b;
      b[0] = (short)f2bf(f0.x); b[1] = (short)f2bf(f0.y);
      b[2] = (short)f2bf(f0.z); b[3] = (short)f2bf(f0.w);
      b[4] = (short)f2bf(f1.x); b[5] = (short)f2bf(f1.y);
      b[6] = (short)f2bf(f1.z); b[7] = (short)f2bf(f1.w);
      acc[n] = __builtin_amdgcn_mfma_f32_16x16x32_bf16(a, b, acc[n], 0, 0, 0);
    }
  }
#pragma unroll
  for (int n = 0; n < 8; ++n) {
    int v = n * 16 + (lane & 15);
    float bias = bfc[v];
#pragma unroll
    for (int i = 0; i < 4; ++i) {
      int m = mt * 16 + (lane >> 4) * 4 + i;
      int s = m >> 6, b = m & 63;
      out[((size_t)b * SS + s) * VV + v] = acc[n][i] + bias;
    }
  }
}

extern "C" void kernel_launch(void* const* d_in, const int* in_sizes, int n_in,
                              void* d_out, int out_size, void* d_ws, size_t ws_size,
                              hipStream_t stream) {
  const int*   x    = (const int*)d_in[0];
  const float* emb  = (const float*)d_in[1];
  const float* W_r  = (const float*)d_in[2];
  const float* U_r  = (const float*)d_in[3];
  const float* b_r  = (const float*)d_in[4];
  const float* W_z  = (const float*)d_in[5];
  const float* U_z  = (const float*)d_in[6];
  const float* b_z  = (const float*)d_in[7];
  const float* W_h  = (const float*)d_in[8];
  const float* U_h  = (const float*)d_in[9];
  const float* b_h  = (const float*)d_in[10];
  const float* W_fc = (const float*)d_in[11];
  const float* b_fc = (const float*)d_in[12];

  char* ws = (char*)d_ws;
  float*          table  = (float*)(ws + WS_TABLE);
  unsigned short* rhbuf  = (unsigned short*)(ws + WS_RH);
  int*            flagsA = (int*)(ws + WS_FLAGS);
  int*            flagsB = (int*)(ws + WS_FLAGS + 1024);
  unsigned short* outs   = (unsigned short*)(ws + WS_OUTS);
  float*          out    = (float*)d_out;
  float*          hlast  = out + (size_t)BB * SS * VV;   // output 1, fp32

  // flags must start at 0 every call (ws is re-poisoned to 0xAA)
  hipMemsetAsync(ws + WS_FLAGS, 0, 2048, stream);

  table_kernel<<<dim3((128 * 3 * 1024) / 256), dim3(256), 0, stream>>>(
      emb, W_r, b_r, W_z, b_z, W_h, b_h, table);

  hipFuncSetAttribute(reinterpret_cast<const void*>(gru_kernel),
                      hipFuncAttributeMaxDynamicSharedMemorySize, LDS_TOTAL);
  void* args[] = {(void*)&x, (void*)&U_r, (void*)&U_z, (void*)&U_h, (void*)&table,
                  (void*)&outs, (void*)&rhbuf, (void*)&hlast, (void*)&flagsA, (void*)&flagsB};
  hipLaunchCooperativeKernel(reinterpret_cast<void*>(gru_kernel), dim3(256), dim3(256),
                             args, (unsigned)LDS_TOTAL, stream);

  logits_kernel<<<dim3(512), dim3(256), 0, stream>>>(outs, W_fc, b_fc, out);
}